// Round 7
// baseline (238.171 us; speedup 1.0000x reference)
//
#include <hip/hip_runtime.h>
#include <math.h>

#define N_ROWS 65536
#define K_CODES 4096
#define NTILES_TOTAL (K_CODES / 32)       // 128
#define K_CHUNKS 2
#define NTILES (NTILES_TOTAL / K_CHUNKS)  // 64 tiles per chunk
#define DIM 64
#define NBUF 4
#define ACC_MARGIN 0.005f   // acc-space gap (= 0.01 in key space), ~16x error bound

typedef __attribute__((ext_vector_type(8))) short bf16x8;
typedef __attribute__((ext_vector_type(4))) float f32x4;

__device__ inline unsigned short f2bf_rne(float f) {
    unsigned u = __float_as_uint(f);
    return (unsigned short)((u + 0x7FFFu + ((u >> 16) & 1u)) >> 16);
}
__device__ inline float bf2f(unsigned short s) {
    return __uint_as_float(((unsigned)s) << 16);
}

// ---------------------------------------------------------------------------
// pack_e: 16x16x32 fragment layout. Frag f = ch*2+kh (ch: code half, kh: k half).
// Lane l elem j <- e[tile*32 + ch*16 + (l&15)][kh*32 + ((l>>4)&3)*8 + j].
// Same index formula used for the in-register x split => k-map cancels in A.B.
// hi frags at tile*8KB + f*1KB, lo at +4KB. Also esq, esqn=-esq/2, count=0.
// ---------------------------------------------------------------------------
__global__ __launch_bounds__(256) void pack_e(const float* __restrict__ embed,
                                              short* __restrict__ e_pk,
                                              float* __restrict__ esq,
                                              float* __restrict__ esqn,
                                              int* __restrict__ count) {
    __shared__ float lds_f[2048];   // 32 codes x 64 dims
    const int tile = blockIdx.x;
    const int t = threadIdx.x;
    if (tile == 0 && t == 0) *count = 0;
    const float4* src = (const float4*)(embed + (size_t)tile * 2048);
    ((float4*)lds_f)[t] = src[t];
    ((float4*)lds_f)[t + 256] = src[t + 256];
    __syncthreads();
    const int l = t & 63;
    const int kh = (t >> 6) & 1;
    const int ch = (t >> 7) & 1;
    const int base = (ch * 16 + (l & 15)) * 64 + kh * 32 + ((l >> 4) & 3) * 8;
    bf16x8 vh, vl;
#pragma unroll
    for (int j = 0; j < 8; ++j) {
        float v = lds_f[base + j];
        unsigned short h = f2bf_rne(v);
        vh[j] = (short)h;
        vl[j] = (short)f2bf_rne(v - bf2f(h));
    }
    *(bf16x8*)(e_pk + (size_t)tile * 4096 + t * 8) = vh;          // f*512 + l*8 == t*8
    *(bf16x8*)(e_pk + (size_t)tile * 4096 + 2048 + t * 8) = vl;
    if (t < 32) {
        float s = 0.f;
#pragma unroll
        for (int d = 0; d < 64; ++d) { float v = lds_f[t * 64 + d]; s = fmaf(v, v, s); }
        esq[tile * 32 + t] = s;
        esqn[tile * 32 + t] = -0.5f * s;
    }
}

// ---------------------------------------------------------------------------
// vq_main: wave = 32 rows; block = 128 rows; one K-chunk (64 tiles) per block.
// 16x16x32 MFMA: 4 independent quadrant chains of 6 (vs one 12-deep chain).
// 4-deep LDS ring, counted vmcnt(6), one raw s_barrier per tile.
// ---------------------------------------------------------------------------
__global__ __launch_bounds__(256, 4) void vq_main(const float* __restrict__ x,
                                                  const short* __restrict__ e_pk,
                                                  const float* __restrict__ esqn,
                                                  float* __restrict__ b1s,
                                                  float* __restrict__ b2s,
                                                  int* __restrict__ i1s) {
    __shared__ __align__(16) char lds[NBUF][8192];   // [hi 4KB][lo 4KB] per slot
    __shared__ __align__(16) float lds_q[NBUF][64];  // staged esqn per slot
    const int tid = threadIdx.x;
    const int wid = tid >> 6;
    const int l = tid & 63;
    const int c16 = l & 15;          // fragment row/col index
    const int rgrp = (l >> 4) & 3;   // k-group / D-row-group selector
    const int kc = blockIdx.x & (K_CHUNKS - 1);
    const int rg = blockIdx.x >> 1;
    const int rowbase = rg * 128 + wid * 32;
    const int tile0 = kc * NTILES;

    // A fragments: on-the-fly hi/lo split, same k-map formula as pack_e.
    bf16x8 ah[2][2], al[2][2];
#pragma unroll
    for (int rh = 0; rh < 2; ++rh) {
        const float* xr = x + (size_t)(rowbase + rh * 16 + c16) * DIM;
#pragma unroll
        for (int kh = 0; kh < 2; ++kh) {
            const float* p = xr + kh * 32 + rgrp * 8;
#pragma unroll
            for (int j = 0; j < 8; ++j) {
                float v = p[j];
                unsigned short h = f2bf_rne(v);
                ah[rh][kh][j] = (short)h;
                al[rh][kh][j] = (short)f2bf_rne(v - bf2f(h));
            }
        }
    }

    // tracked state: element (q*4+j), q = rh*2+ch
    float b1[16], b2[16];
    int i1[16];
#pragma unroll
    for (int i = 0; i < 16; ++i) { b1[i] = -3.0e38f; b2[i] = -3.0e38f; i1[i] = 0; }

    // 3 VMEM ops per stage (hi 16B, lo 16B, esqn 4B).
    auto stage = [&](int t, int b) {
        const char* gsrc = (const char*)e_pk + (size_t)(tile0 + t) * 8192 + tid * 16;
        __builtin_amdgcn_global_load_lds(
            (const __attribute__((address_space(1))) void*)gsrc,
            (__attribute__((address_space(3))) void*)(&lds[b][wid * 1024]), 16, 0, 0);
        __builtin_amdgcn_global_load_lds(
            (const __attribute__((address_space(1))) void*)(gsrc + 4096),
            (__attribute__((address_space(3))) void*)(&lds[b][4096 + wid * 1024]), 16, 0, 0);
        const float* qsrc = esqn + (size_t)(tile0 + t) * 32 + l;
        __builtin_amdgcn_global_load_lds(
            (const __attribute__((address_space(1))) void*)qsrc,
            (__attribute__((address_space(3))) void*)(&lds_q[b][0]), 4, 0, 0);
    };

    stage(0, 0);
    stage(1, 1);

    for (int t = 0; t < NTILES; ++t) {
        const int cur = t & (NBUF - 1);
        if (t + 2 < NTILES) stage(t + 2, (t + 2) & (NBUF - 1));
        asm volatile("s_waitcnt vmcnt(6)" ::: "memory");
        __builtin_amdgcn_sched_barrier(0);
        __builtin_amdgcn_s_barrier();
        __builtin_amdgcn_sched_barrier(0);

        const float eq0 = lds_q[cur][c16];        // esqn for cols 0-15
        const float eq1 = lds_q[cur][16 + c16];   // esqn for cols 16-31
        const int ci0 = (tile0 + t) * 32 + c16;
        const int ci1 = ci0 + 16;

        // B fragments: frag f = ch*2+kh at byte offset f*1024 + l*16 (hi), +4096 (lo)
        bf16x8 bh[2][2], bl[2][2];
#pragma unroll
        for (int ch = 0; ch < 2; ++ch)
#pragma unroll
            for (int kh = 0; kh < 2; ++kh) {
                const int fo = ((ch * 2 + kh) * 64 + l) * 16;
                bh[ch][kh] = *(const bf16x8*)(&lds[cur][fo]);
                bl[ch][kh] = *(const bf16x8*)(&lds[cur][4096 + fo]);
            }

        // 4 independent quadrant accumulators (C-init = -e^2/2 of own cols).
        f32x4 a00 = {eq0, eq0, eq0, eq0};   // rh0, ch0
        f32x4 a01 = {eq1, eq1, eq1, eq1};   // rh0, ch1
        f32x4 a10 = {eq0, eq0, eq0, eq0};   // rh1, ch0
        f32x4 a11 = {eq1, eq1, eq1, eq1};   // rh1, ch1

        __builtin_amdgcn_s_setprio(1);
#pragma unroll
        for (int kh = 0; kh < 2; ++kh) {
            a00 = __builtin_amdgcn_mfma_f32_16x16x32_bf16(ah[0][kh], bh[0][kh], a00, 0, 0, 0);
            a01 = __builtin_amdgcn_mfma_f32_16x16x32_bf16(ah[0][kh], bh[1][kh], a01, 0, 0, 0);
            a10 = __builtin_amdgcn_mfma_f32_16x16x32_bf16(ah[1][kh], bh[0][kh], a10, 0, 0, 0);
            a11 = __builtin_amdgcn_mfma_f32_16x16x32_bf16(ah[1][kh], bh[1][kh], a11, 0, 0, 0);
            a00 = __builtin_amdgcn_mfma_f32_16x16x32_bf16(ah[0][kh], bl[0][kh], a00, 0, 0, 0);
            a01 = __builtin_amdgcn_mfma_f32_16x16x32_bf16(ah[0][kh], bl[1][kh], a01, 0, 0, 0);
            a10 = __builtin_amdgcn_mfma_f32_16x16x32_bf16(ah[1][kh], bl[0][kh], a10, 0, 0, 0);
            a11 = __builtin_amdgcn_mfma_f32_16x16x32_bf16(ah[1][kh], bl[1][kh], a11, 0, 0, 0);
            a00 = __builtin_amdgcn_mfma_f32_16x16x32_bf16(al[0][kh], bh[0][kh], a00, 0, 0, 0);
            a01 = __builtin_amdgcn_mfma_f32_16x16x32_bf16(al[0][kh], bh[1][kh], a01, 0, 0, 0);
            a10 = __builtin_amdgcn_mfma_f32_16x16x32_bf16(al[1][kh], bh[0][kh], a10, 0, 0, 0);
            a11 = __builtin_amdgcn_mfma_f32_16x16x32_bf16(al[1][kh], bh[1][kh], a11, 0, 0, 0);
        }
        __builtin_amdgcn_s_setprio(0);

        // argmax tracking: 4 VALU per element.
#define TRACK(ACC, Q, CIDX)                                         \
        _Pragma("unroll")                                           \
        for (int j = 0; j < 4; ++j) {                               \
            float val = (ACC)[j];                                   \
            int e = (Q) * 4 + j;                                    \
            bool gt = val > b1[e];                                  \
            b2[e] = __builtin_amdgcn_fmed3f(val, b1[e], b2[e]);     \
            b1[e] = fmaxf(val, b1[e]);                              \
            i1[e] = gt ? (CIDX) : i1[e];                            \
        }
        TRACK(a00, 0, ci0)
        TRACK(a01, 1, ci1)
        TRACK(a10, 2, ci0)
        TRACK(a11, 3, ci1)
#undef TRACK
    }

    // Step 1: butterfly over the 16 lanes of each col group (xor bits 0-3
    // preserve rgrp = bits 4-5).
#pragma unroll
    for (int e = 0; e < 16; ++e) {
#pragma unroll
        for (int m = 1; m <= 8; m <<= 1) {
            float ob1 = __shfl_xor(b1[e], m);
            float ob2 = __shfl_xor(b2[e], m);
            int oi = __shfl_xor(i1[e], m);
            float nb2 = fmaxf(fminf(b1[e], ob1), fmaxf(b2[e], ob2));
            bool take = ob1 > b1[e];
            b1[e] = take ? ob1 : b1[e];
            i1[e] = take ? oi : i1[e];
            b2[e] = nb2;
        }
    }

    // Step 2: merge the two col-halves (ch) per (rh, j); step 3: write.
    if (c16 == 0) {
#pragma unroll
        for (int rh = 0; rh < 2; ++rh)
#pragma unroll
            for (int j = 0; j < 4; ++j) {
                int ea = (rh * 2 + 0) * 4 + j;
                int eb = (rh * 2 + 1) * 4 + j;
                bool take = b1[eb] > b1[ea];   // tie -> ch0 (lower idx); ties rescored
                float m1 = fmaxf(b1[ea], b1[eb]);
                float m2 = fmaxf(fminf(b1[ea], b1[eb]), fmaxf(b2[ea], b2[eb]));
                int idx = take ? i1[eb] : i1[ea];
                int row = rowbase + rh * 16 + rgrp * 4 + j;   // m89 D-row map
                b1s[(size_t)kc * N_ROWS + row] = m1;
                b2s[(size_t)kc * N_ROWS + row] = m2;
                i1s[(size_t)kc * N_ROWS + row] = idx;
            }
    }
}

// ---------------------------------------------------------------------------
// vq_merge_gather: merge the 2 chunks per row, flag close calls, write
// out_ind + out_q (8 threads per row).
// ---------------------------------------------------------------------------
__global__ __launch_bounds__(256) void vq_merge_gather(const float* __restrict__ embed,
                                                       const float* __restrict__ b1s,
                                                       const float* __restrict__ b2s,
                                                       const int* __restrict__ i1s,
                                                       float* __restrict__ out_q,
                                                       float* __restrict__ out_ind,
                                                       int* __restrict__ list,
                                                       int* __restrict__ count) {
    int t = blockIdx.x * 256 + threadIdx.x;
    int r = t >> 3, q = t & 7;
    float ab1 = b1s[r], bb1 = b1s[N_ROWS + r];
    float ab2 = b2s[r], bb2 = b2s[N_ROWS + r];
    int ai = i1s[r], bi = i1s[N_ROWS + r];
    bool take = bb1 > ab1;                 // tie -> chunk 0 (lower index); ties flagged anyway
    int idx = take ? bi : ai;
    float m1 = fmaxf(ab1, bb1);
    float m2 = fmaxf(fminf(ab1, bb1), fmaxf(ab2, bb2));
    const float4* src = (const float4*)(embed + (size_t)idx * DIM + q * 8);
    float4* dst = (float4*)(out_q + (size_t)r * DIM + q * 8);
    dst[0] = src[0];
    dst[1] = src[1];
    if (q == 0) {
        out_ind[r] = (float)idx;
        if (m1 - m2 < ACC_MARGIN) {
            int p = atomicAdd(count, 1);
            list[p] = r;
        }
    }
}

// ---------------------------------------------------------------------------
// vq_rescore: exact fp32 full rescan of flagged rows; patches out directly.
// ---------------------------------------------------------------------------
__global__ __launch_bounds__(256) void vq_rescore(const float* __restrict__ x,
                                                  const float* __restrict__ embed,
                                                  const float* __restrict__ esq,
                                                  const int* __restrict__ list,
                                                  const int* __restrict__ count,
                                                  float* __restrict__ out_q,
                                                  float* __restrict__ out_ind) {
    __shared__ float xs[64];
    __shared__ float sk[256];
    __shared__ int si[256];
    const int tid = threadIdx.x;
    const int n = *count;
    for (int f = blockIdx.x; f < n; f += gridDim.x) {
        const int row = list[f];
        if (tid < 16) ((float4*)xs)[tid] = ((const float4*)(x + (size_t)row * DIM))[tid];
        __syncthreads();
        float best = 3.0e38f;
        int bi = 0;
        for (int i = 0; i < 16; ++i) {
            int c = tid + (i << 8);
            const float* e = embed + (size_t)c * DIM;
            float d0 = 0, d1 = 0, d2 = 0, d3 = 0;
#pragma unroll
            for (int d = 0; d < 64; d += 4) {
                d0 = fmaf(xs[d + 0], e[d + 0], d0);
                d1 = fmaf(xs[d + 1], e[d + 1], d1);
                d2 = fmaf(xs[d + 2], e[d + 2], d2);
                d3 = fmaf(xs[d + 3], e[d + 3], d3);
            }
            float key = fmaf(-2.f, (d0 + d1) + (d2 + d3), esq[c]);
            if (key < best) { best = key; bi = c; }   // c ascending -> first-min
        }
        sk[tid] = best; si[tid] = bi;
        __syncthreads();
        for (int s = 128; s > 0; s >>= 1) {
            if (tid < s) {
                float ok = sk[tid + s]; int oi = si[tid + s];
                if (ok < sk[tid] || (ok == sk[tid] && oi < si[tid])) { sk[tid] = ok; si[tid] = oi; }
            }
            __syncthreads();
        }
        if (tid == 0) out_ind[row] = (float)si[0];
        if (tid < 16) {
            const float4* src = (const float4*)(embed + (size_t)si[0] * DIM);
            ((float4*)(out_q + (size_t)row * DIM))[tid] = src[tid];
        }
        __syncthreads();
    }
}

// ---------------------------------------------------------------------------
extern "C" void kernel_launch(void* const* d_in, const int* in_sizes, int n_in,
                              void* d_out, int out_size, void* d_ws, size_t ws_size,
                              hipStream_t stream) {
    const float* x = (const float*)d_in[0];      // [N, D] fp32
    const float* embed = (const float*)d_in[1];  // [1, K, D] fp32
    float* out = (float*)d_out;                  // [N*D quantize][N indices]
    float* out_ind = out + (size_t)N_ROWS * DIM;

    char* ws = (char*)d_ws;
    short* e_pk = (short*)ws;                            // 1 MB
    size_t off = 1 << 20;
    float* esq = (float*)(ws + off);  off += 17 << 10;   // 16 KB (+pad)
    float* esqn = (float*)(ws + off); off += 17 << 10;   // 16 KB + 64-float stage pad
    float* b1s = (float*)(ws + off);  off += (size_t)K_CHUNKS * N_ROWS * 4;
    float* b2s = (float*)(ws + off);  off += (size_t)K_CHUNKS * N_ROWS * 4;
    int* i1s = (int*)(ws + off);      off += (size_t)K_CHUNKS * N_ROWS * 4;
    int* list = (int*)(ws + off);     off += (size_t)N_ROWS * 4;
    int* count = (int*)(ws + off);

    pack_e<<<NTILES_TOTAL, 256, 0, stream>>>(embed, e_pk, esq, esqn, count);
    vq_main<<<(N_ROWS / 128) * K_CHUNKS, 256, 0, stream>>>(x, e_pk, esqn, b1s, b2s, i1s);
    vq_merge_gather<<<N_ROWS * 8 / 256, 256, 0, stream>>>(embed, b1s, b2s, i1s,
                                                          out, out_ind, list, count);
    vq_rescore<<<512, 256, 0, stream>>>(x, embed, esq, list, count, out, out_ind);
}

// Round 8
// 146.874 us; speedup vs baseline: 1.6216x; 1.6216x over previous
//
#include <hip/hip_runtime.h>
#include <math.h>

#define N_ROWS 65536
#define K_CODES 4096
#define NTILES_TOTAL (K_CODES / 32)       // 128
#define K_CHUNKS 2
#define NTILES (NTILES_TOTAL / K_CHUNKS)  // 64 tiles per chunk
#define DIM 64
#define NBUF 4
#define ACC_MARGIN 0.005f   // acc-space gap (= 0.01 in key space), ~16x error bound

typedef __attribute__((ext_vector_type(8))) short bf16x8;
typedef __attribute__((ext_vector_type(4))) float f32x4;

__device__ inline unsigned short f2bf_rne(float f) {
    unsigned u = __float_as_uint(f);
    return (unsigned short)((u + 0x7FFFu + ((u >> 16) & 1u)) >> 16);
}
__device__ inline float bf2f(unsigned short s) {
    return __uint_as_float(((unsigned)s) << 16);
}

// ---------------------------------------------------------------------------
// pack_e: 16x16x32 fragment layout. Frag f = ch*2+kh (ch: code half, kh: k half).
// Lane l elem j <- e[tile*32 + ch*16 + (l&15)][kh*32 + ((l>>4)&3)*8 + j].
// Same index formula used for the in-register x split => k-map cancels in A.B.
// hi frags at tile*8KB + f*1KB, lo at +4KB. Also esq, esqn=-esq/2, count=0.
// ---------------------------------------------------------------------------
__global__ __launch_bounds__(256) void pack_e(const float* __restrict__ embed,
                                              short* __restrict__ e_pk,
                                              float* __restrict__ esq,
                                              float* __restrict__ esqn,
                                              int* __restrict__ count) {
    __shared__ float lds_f[2048];   // 32 codes x 64 dims
    const int tile = blockIdx.x;
    const int t = threadIdx.x;
    if (tile == 0 && t == 0) *count = 0;
    const float4* src = (const float4*)(embed + (size_t)tile * 2048);
    ((float4*)lds_f)[t] = src[t];
    ((float4*)lds_f)[t + 256] = src[t + 256];
    __syncthreads();
    const int l = t & 63;
    const int kh = (t >> 6) & 1;
    const int ch = (t >> 7) & 1;
    const int base = (ch * 16 + (l & 15)) * 64 + kh * 32 + ((l >> 4) & 3) * 8;
    bf16x8 vh, vl;
#pragma unroll
    for (int j = 0; j < 8; ++j) {
        float v = lds_f[base + j];
        unsigned short h = f2bf_rne(v);
        vh[j] = (short)h;
        vl[j] = (short)f2bf_rne(v - bf2f(h));
    }
    *(bf16x8*)(e_pk + (size_t)tile * 4096 + t * 8) = vh;          // f*512 + l*8 == t*8
    *(bf16x8*)(e_pk + (size_t)tile * 4096 + 2048 + t * 8) = vl;
    if (t < 32) {
        float s = 0.f;
#pragma unroll
        for (int d = 0; d < 64; ++d) { float v = lds_f[t * 64 + d]; s = fmaf(v, v, s); }
        esq[tile * 32 + t] = s;
        esqn[tile * 32 + t] = -0.5f * s;
    }
}

// ---------------------------------------------------------------------------
// vq_main: wave = 32 rows; block = 128 rows; one K-chunk (64 tiles) per block.
// 16x16x32 MFMA: 4 independent 6-deep quadrant chains. B frags loaded per-kh
// (16 live VGPRs); col-halves merged into 8 per-row trackers each tile
// (24 tracking VGPRs). 4-deep LDS ring, counted vmcnt(6), one barrier/tile.
// ---------------------------------------------------------------------------
__global__ __launch_bounds__(256, 4) void vq_main(const float* __restrict__ x,
                                                  const short* __restrict__ e_pk,
                                                  const float* __restrict__ esqn,
                                                  float* __restrict__ b1s,
                                                  float* __restrict__ b2s,
                                                  int* __restrict__ i1s) {
    __shared__ __align__(16) char lds[NBUF][8192];   // [hi 4KB][lo 4KB] per slot
    __shared__ __align__(16) float lds_q[NBUF][64];  // staged esqn per slot
    const int tid = threadIdx.x;
    const int wid = tid >> 6;
    const int l = tid & 63;
    const int c16 = l & 15;          // fragment col index
    const int rgrp = (l >> 4) & 3;   // k-group / D-row-group selector
    const int kc = blockIdx.x & (K_CHUNKS - 1);
    const int rg = blockIdx.x >> 1;
    const int rowbase = rg * 128 + wid * 32;
    const int tile0 = kc * NTILES;

    // A fragments: on-the-fly hi/lo split, same k-map formula as pack_e.
    bf16x8 ah[2][2], al[2][2];   // [rh][kh]
#pragma unroll
    for (int rh = 0; rh < 2; ++rh) {
        const float* xr = x + (size_t)(rowbase + rh * 16 + c16) * DIM;
#pragma unroll
        for (int kh = 0; kh < 2; ++kh) {
            const float* p = xr + kh * 32 + rgrp * 8;
#pragma unroll
            for (int j = 0; j < 8; ++j) {
                float v = p[j];
                unsigned short h = f2bf_rne(v);
                ah[rh][kh][j] = (short)h;
                al[rh][kh][j] = (short)f2bf_rne(v - bf2f(h));
            }
        }
    }

    // Per-row trackers: slot e = rh*4 + j  (8 rows this lane contributes to).
    float b1[8], b2[8];
    int i1[8];
#pragma unroll
    for (int i = 0; i < 8; ++i) { b1[i] = -3.0e38f; b2[i] = -3.0e38f; i1[i] = 0; }

    // 3 VMEM ops per stage (hi 16B, lo 16B, esqn 4B).
    auto stage = [&](int t, int b) {
        const char* gsrc = (const char*)e_pk + (size_t)(tile0 + t) * 8192 + tid * 16;
        __builtin_amdgcn_global_load_lds(
            (const __attribute__((address_space(1))) void*)gsrc,
            (__attribute__((address_space(3))) void*)(&lds[b][wid * 1024]), 16, 0, 0);
        __builtin_amdgcn_global_load_lds(
            (const __attribute__((address_space(1))) void*)(gsrc + 4096),
            (__attribute__((address_space(3))) void*)(&lds[b][4096 + wid * 1024]), 16, 0, 0);
        const float* qsrc = esqn + (size_t)(tile0 + t) * 32 + l;
        __builtin_amdgcn_global_load_lds(
            (const __attribute__((address_space(1))) void*)qsrc,
            (__attribute__((address_space(3))) void*)(&lds_q[b][0]), 4, 0, 0);
    };

    stage(0, 0);
    stage(1, 1);

    for (int t = 0; t < NTILES; ++t) {
        const int cur = t & (NBUF - 1);
        if (t + 2 < NTILES) stage(t + 2, (t + 2) & (NBUF - 1));
        asm volatile("s_waitcnt vmcnt(6)" ::: "memory");
        __builtin_amdgcn_sched_barrier(0);
        __builtin_amdgcn_s_barrier();
        __builtin_amdgcn_sched_barrier(0);

        const float eq0 = lds_q[cur][c16];        // esqn, cols 0-15
        const float eq1 = lds_q[cur][16 + c16];   // esqn, cols 16-31
        const int ci0 = (tile0 + t) * 32 + c16;
        const int ci1 = ci0 + 16;

        // 4 independent quadrant accumulators (C-init = -e^2/2 of own cols).
        f32x4 a00 = {eq0, eq0, eq0, eq0};   // rh0, ch0
        f32x4 a01 = {eq1, eq1, eq1, eq1};   // rh0, ch1
        f32x4 a10 = {eq0, eq0, eq0, eq0};   // rh1, ch0
        f32x4 a11 = {eq1, eq1, eq1, eq1};   // rh1, ch1

        __builtin_amdgcn_s_setprio(1);
#pragma unroll
        for (int kh = 0; kh < 2; ++kh) {
            // B frags for this kh only (16 live VGPRs): frag f = ch*2+kh.
            const int fo0 = ((0 * 2 + kh) * 64 + l) * 16;
            const int fo1 = ((1 * 2 + kh) * 64 + l) * 16;
            const bf16x8 bh0 = *(const bf16x8*)(&lds[cur][fo0]);
            const bf16x8 bh1 = *(const bf16x8*)(&lds[cur][fo1]);
            const bf16x8 bl0 = *(const bf16x8*)(&lds[cur][4096 + fo0]);
            const bf16x8 bl1 = *(const bf16x8*)(&lds[cur][4096 + fo1]);
            a00 = __builtin_amdgcn_mfma_f32_16x16x32_bf16(ah[0][kh], bh0, a00, 0, 0, 0);
            a01 = __builtin_amdgcn_mfma_f32_16x16x32_bf16(ah[0][kh], bh1, a01, 0, 0, 0);
            a10 = __builtin_amdgcn_mfma_f32_16x16x32_bf16(ah[1][kh], bh0, a10, 0, 0, 0);
            a11 = __builtin_amdgcn_mfma_f32_16x16x32_bf16(ah[1][kh], bh1, a11, 0, 0, 0);
            a00 = __builtin_amdgcn_mfma_f32_16x16x32_bf16(ah[0][kh], bl0, a00, 0, 0, 0);
            a01 = __builtin_amdgcn_mfma_f32_16x16x32_bf16(ah[0][kh], bl1, a01, 0, 0, 0);
            a10 = __builtin_amdgcn_mfma_f32_16x16x32_bf16(ah[1][kh], bl0, a10, 0, 0, 0);
            a11 = __builtin_amdgcn_mfma_f32_16x16x32_bf16(ah[1][kh], bl1, a11, 0, 0, 0);
            a00 = __builtin_amdgcn_mfma_f32_16x16x32_bf16(al[0][kh], bh0, a00, 0, 0, 0);
            a01 = __builtin_amdgcn_mfma_f32_16x16x32_bf16(al[0][kh], bh1, a01, 0, 0, 0);
            a10 = __builtin_amdgcn_mfma_f32_16x16x32_bf16(al[1][kh], bh0, a10, 0, 0, 0);
            a11 = __builtin_amdgcn_mfma_f32_16x16x32_bf16(al[1][kh], bh1, a11, 0, 0, 0);
        }
        __builtin_amdgcn_s_setprio(0);

        // Track per row: ch0 candidate then ch1 (ascending index -> first-min).
#define TRACK2(V0, V1, E)                                            \
        {                                                            \
            float v0 = (V0), v1 = (V1);                              \
            bool g0 = v0 > b1[E];                                    \
            b2[E] = __builtin_amdgcn_fmed3f(v0, b1[E], b2[E]);       \
            b1[E] = fmaxf(v0, b1[E]);                                \
            i1[E] = g0 ? ci0 : i1[E];                                \
            bool g1 = v1 > b1[E];                                    \
            b2[E] = __builtin_amdgcn_fmed3f(v1, b1[E], b2[E]);       \
            b1[E] = fmaxf(v1, b1[E]);                                \
            i1[E] = g1 ? ci1 : i1[E];                                \
        }
#pragma unroll
        for (int j = 0; j < 4; ++j) {
            TRACK2(a00[j], a01[j], j)
            TRACK2(a10[j], a11[j], 4 + j)
        }
#undef TRACK2
    }

    // Butterfly over the 16 col lanes (xor bits 0-3 preserve rgrp).
#pragma unroll
    for (int e = 0; e < 8; ++e) {
#pragma unroll
        for (int m = 1; m <= 8; m <<= 1) {
            float ob1 = __shfl_xor(b1[e], m);
            float ob2 = __shfl_xor(b2[e], m);
            int oi = __shfl_xor(i1[e], m);
            float nb2 = fmaxf(fminf(b1[e], ob1), fmaxf(b2[e], ob2));
            bool take = ob1 > b1[e];
            b1[e] = take ? ob1 : b1[e];
            i1[e] = take ? oi : i1[e];
            b2[e] = nb2;
        }
        if (c16 == 0) {
            int row = rowbase + (e >> 2) * 16 + rgrp * 4 + (e & 3);  // m89 D-row map
            b1s[(size_t)kc * N_ROWS + row] = b1[e];
            b2s[(size_t)kc * N_ROWS + row] = b2[e];
            i1s[(size_t)kc * N_ROWS + row] = i1[e];
        }
    }
}

// ---------------------------------------------------------------------------
// vq_merge_gather: merge the 2 chunks per row, flag close calls, write
// out_ind + out_q (8 threads per row).
// ---------------------------------------------------------------------------
__global__ __launch_bounds__(256) void vq_merge_gather(const float* __restrict__ embed,
                                                       const float* __restrict__ b1s,
                                                       const float* __restrict__ b2s,
                                                       const int* __restrict__ i1s,
                                                       float* __restrict__ out_q,
                                                       float* __restrict__ out_ind,
                                                       int* __restrict__ list,
                                                       int* __restrict__ count) {
    int t = blockIdx.x * 256 + threadIdx.x;
    int r = t >> 3, q = t & 7;
    float ab1 = b1s[r], bb1 = b1s[N_ROWS + r];
    float ab2 = b2s[r], bb2 = b2s[N_ROWS + r];
    int ai = i1s[r], bi = i1s[N_ROWS + r];
    bool take = bb1 > ab1;                 // tie -> chunk 0 (lower index); ties flagged anyway
    int idx = take ? bi : ai;
    float m1 = fmaxf(ab1, bb1);
    float m2 = fmaxf(fminf(ab1, bb1), fmaxf(ab2, bb2));
    const float4* src = (const float4*)(embed + (size_t)idx * DIM + q * 8);
    float4* dst = (float4*)(out_q + (size_t)r * DIM + q * 8);
    dst[0] = src[0];
    dst[1] = src[1];
    if (q == 0) {
        out_ind[r] = (float)idx;
        if (m1 - m2 < ACC_MARGIN) {
            int p = atomicAdd(count, 1);
            list[p] = r;
        }
    }
}

// ---------------------------------------------------------------------------
// vq_rescore: exact fp32 full rescan of flagged rows; patches out directly.
// ---------------------------------------------------------------------------
__global__ __launch_bounds__(256) void vq_rescore(const float* __restrict__ x,
                                                  const float* __restrict__ embed,
                                                  const float* __restrict__ esq,
                                                  const int* __restrict__ list,
                                                  const int* __restrict__ count,
                                                  float* __restrict__ out_q,
                                                  float* __restrict__ out_ind) {
    __shared__ float xs[64];
    __shared__ float sk[256];
    __shared__ int si[256];
    const int tid = threadIdx.x;
    const int n = *count;
    for (int f = blockIdx.x; f < n; f += gridDim.x) {
        const int row = list[f];
        if (tid < 16) ((float4*)xs)[tid] = ((const float4*)(x + (size_t)row * DIM))[tid];
        __syncthreads();
        float best = 3.0e38f;
        int bi = 0;
        for (int i = 0; i < 16; ++i) {
            int c = tid + (i << 8);
            const float* e = embed + (size_t)c * DIM;
            float d0 = 0, d1 = 0, d2 = 0, d3 = 0;
#pragma unroll
            for (int d = 0; d < 64; d += 4) {
                d0 = fmaf(xs[d + 0], e[d + 0], d0);
                d1 = fmaf(xs[d + 1], e[d + 1], d1);
                d2 = fmaf(xs[d + 2], e[d + 2], d2);
                d3 = fmaf(xs[d + 3], e[d + 3], d3);
            }
            float key = fmaf(-2.f, (d0 + d1) + (d2 + d3), esq[c]);
            if (key < best) { best = key; bi = c; }   // c ascending -> first-min
        }
        sk[tid] = best; si[tid] = bi;
        __syncthreads();
        for (int s = 128; s > 0; s >>= 1) {
            if (tid < s) {
                float ok = sk[tid + s]; int oi = si[tid + s];
                if (ok < sk[tid] || (ok == sk[tid] && oi < si[tid])) { sk[tid] = ok; si[tid] = oi; }
            }
            __syncthreads();
        }
        if (tid == 0) out_ind[row] = (float)si[0];
        if (tid < 16) {
            const float4* src = (const float4*)(embed + (size_t)si[0] * DIM);
            ((float4*)(out_q + (size_t)row * DIM))[tid] = src[tid];
        }
        __syncthreads();
    }
}

// ---------------------------------------------------------------------------
extern "C" void kernel_launch(void* const* d_in, const int* in_sizes, int n_in,
                              void* d_out, int out_size, void* d_ws, size_t ws_size,
                              hipStream_t stream) {
    const float* x = (const float*)d_in[0];      // [N, D] fp32
    const float* embed = (const float*)d_in[1];  // [1, K, D] fp32
    float* out = (float*)d_out;                  // [N*D quantize][N indices]
    float* out_ind = out + (size_t)N_ROWS * DIM;

    char* ws = (char*)d_ws;
    short* e_pk = (short*)ws;                            // 1 MB
    size_t off = 1 << 20;
    float* esq = (float*)(ws + off);  off += 17 << 10;   // 16 KB (+pad)
    float* esqn = (float*)(ws + off); off += 17 << 10;   // 16 KB + 64-float stage pad
    float* b1s = (float*)(ws + off);  off += (size_t)K_CHUNKS * N_ROWS * 4;
    float* b2s = (float*)(ws + off);  off += (size_t)K_CHUNKS * N_ROWS * 4;
    int* i1s = (int*)(ws + off);      off += (size_t)K_CHUNKS * N_ROWS * 4;
    int* list = (int*)(ws + off);     off += (size_t)N_ROWS * 4;
    int* count = (int*)(ws + off);

    pack_e<<<NTILES_TOTAL, 256, 0, stream>>>(embed, e_pk, esq, esqn, count);
    vq_main<<<(N_ROWS / 128) * K_CHUNKS, 256, 0, stream>>>(x, e_pk, esqn, b1s, b2s, i1s);
    vq_merge_gather<<<N_ROWS * 8 / 256, 256, 0, stream>>>(embed, b1s, b2s, i1s,
                                                          out, out_ind, list, count);
    vq_rescore<<<512, 256, 0, stream>>>(x, embed, esq, list, count, out, out_ind);
}

// Round 9
// 146.515 us; speedup vs baseline: 1.6256x; 1.0024x over previous
//
#include <hip/hip_runtime.h>
#include <math.h>

#define N_ROWS 65536
#define K_CODES 4096
#define NTILES_TOTAL (K_CODES / 32)       // 128
#define K_CHUNKS 2
#define NTILES (NTILES_TOTAL / K_CHUNKS)  // 64 tiles per chunk
#define DIM 64
#define NBUF 2
#define ACC_MARGIN 0.005f   // acc-space gap (= 0.01 in key space), ~16x error bound

typedef __attribute__((ext_vector_type(8))) short bf16x8;
typedef __attribute__((ext_vector_type(4))) float f32x4;

__device__ inline unsigned short f2bf_rne(float f) {
    unsigned u = __float_as_uint(f);
    return (unsigned short)((u + 0x7FFFu + ((u >> 16) & 1u)) >> 16);
}
__device__ inline float bf2f(unsigned short s) {
    return __uint_as_float(((unsigned)s) << 16);
}

// ---------------------------------------------------------------------------
// pack_e: 16x16x32 fragment layout. Frag f = ch*2+kh (ch: code half, kh: k half).
// Lane l elem j <- e[tile*32 + ch*16 + (l&15)][kh*32 + ((l>>4)&3)*8 + j].
// Same index formula used for the in-register x split => k-map cancels in A.B.
// hi frags at tile*8KB + f*1KB, lo at +4KB. Also esq, esqn=-esq/2, count=0.
// ---------------------------------------------------------------------------
__global__ __launch_bounds__(256) void pack_e(const float* __restrict__ embed,
                                              short* __restrict__ e_pk,
                                              float* __restrict__ esq,
                                              float* __restrict__ esqn,
                                              int* __restrict__ count) {
    __shared__ float lds_f[2048];   // 32 codes x 64 dims
    const int tile = blockIdx.x;
    const int t = threadIdx.x;
    if (tile == 0 && t == 0) *count = 0;
    const float4* src = (const float4*)(embed + (size_t)tile * 2048);
    ((float4*)lds_f)[t] = src[t];
    ((float4*)lds_f)[t + 256] = src[t + 256];
    __syncthreads();
    const int l = t & 63;
    const int kh = (t >> 6) & 1;
    const int ch = (t >> 7) & 1;
    const int base = (ch * 16 + (l & 15)) * 64 + kh * 32 + ((l >> 4) & 3) * 8;
    bf16x8 vh, vl;
#pragma unroll
    for (int j = 0; j < 8; ++j) {
        float v = lds_f[base + j];
        unsigned short h = f2bf_rne(v);
        vh[j] = (short)h;
        vl[j] = (short)f2bf_rne(v - bf2f(h));
    }
    *(bf16x8*)(e_pk + (size_t)tile * 4096 + t * 8) = vh;          // f*512 + l*8 == t*8
    *(bf16x8*)(e_pk + (size_t)tile * 4096 + 2048 + t * 8) = vl;
    if (t < 32) {
        float s = 0.f;
#pragma unroll
        for (int d = 0; d < 64; ++d) { float v = lds_f[t * 64 + d]; s = fmaf(v, v, s); }
        esq[tile * 32 + t] = s;
        esqn[tile * 32 + t] = -0.5f * s;
    }
}

// ---------------------------------------------------------------------------
// vq_main: wave = 32 rows; block = 128 rows; one K-chunk (64 tiles) per block.
// NBUF=2, ONE barrier/tile with full drain; stage(t+1) issued AFTER the
// barrier so ds_reads/MFMA/track of different waves overlap instead of
// phase-locking. All 8 B frags read up-front (fits reg budget; R8 used 60).
// ---------------------------------------------------------------------------
__global__ __launch_bounds__(256, 4) void vq_main(const float* __restrict__ x,
                                                  const short* __restrict__ e_pk,
                                                  const float* __restrict__ esqn,
                                                  float* __restrict__ b1s,
                                                  float* __restrict__ b2s,
                                                  int* __restrict__ i1s) {
    __shared__ __align__(16) char lds[NBUF][8192];   // [hi 4KB][lo 4KB] per slot
    __shared__ __align__(16) float lds_q[NBUF][64];  // staged esqn per slot
    const int tid = threadIdx.x;
    const int wid = tid >> 6;
    const int l = tid & 63;
    const int c16 = l & 15;          // fragment col index
    const int rgrp = (l >> 4) & 3;   // k-group / D-row-group selector
    const int kc = blockIdx.x & (K_CHUNKS - 1);
    const int rg = blockIdx.x >> 1;
    const int rowbase = rg * 128 + wid * 32;
    const int tile0 = kc * NTILES;

    // A fragments: on-the-fly hi/lo split, same k-map formula as pack_e.
    bf16x8 ah[2][2], al[2][2];   // [rh][kh]
#pragma unroll
    for (int rh = 0; rh < 2; ++rh) {
        const float* xr = x + (size_t)(rowbase + rh * 16 + c16) * DIM;
#pragma unroll
        for (int kh = 0; kh < 2; ++kh) {
            const float* p = xr + kh * 32 + rgrp * 8;
#pragma unroll
            for (int j = 0; j < 8; ++j) {
                float v = p[j];
                unsigned short h = f2bf_rne(v);
                ah[rh][kh][j] = (short)h;
                al[rh][kh][j] = (short)f2bf_rne(v - bf2f(h));
            }
        }
    }

    // Per-row trackers: slot e = rh*4 + j  (8 rows this lane contributes to).
    float b1[8], b2[8];
    int i1[8];
#pragma unroll
    for (int i = 0; i < 8; ++i) { b1[i] = -3.0e38f; b2[i] = -3.0e38f; i1[i] = 0; }

    // 3 VMEM ops per stage (hi 16B, lo 16B, esqn 4B).
    auto stage = [&](int t, int b) {
        const char* gsrc = (const char*)e_pk + (size_t)(tile0 + t) * 8192 + tid * 16;
        __builtin_amdgcn_global_load_lds(
            (const __attribute__((address_space(1))) void*)gsrc,
            (__attribute__((address_space(3))) void*)(&lds[b][wid * 1024]), 16, 0, 0);
        __builtin_amdgcn_global_load_lds(
            (const __attribute__((address_space(1))) void*)(gsrc + 4096),
            (__attribute__((address_space(3))) void*)(&lds[b][4096 + wid * 1024]), 16, 0, 0);
        const float* qsrc = esqn + (size_t)(tile0 + t) * 32 + l;
        __builtin_amdgcn_global_load_lds(
            (const __attribute__((address_space(1))) void*)qsrc,
            (__attribute__((address_space(3))) void*)(&lds_q[b][0]), 4, 0, 0);
    };

    stage(0, 0);

    for (int t = 0; t < NTILES; ++t) {
        const int cur = t & 1;
        // Drain: my stage(t) landed + my ds_reads of slot cur^1 retired.
        // Barrier => true for ALL waves: tile t fully in LDS, slot cur^1 free.
        asm volatile("s_waitcnt vmcnt(0) lgkmcnt(0)" ::: "memory");
        __builtin_amdgcn_sched_barrier(0);
        __builtin_amdgcn_s_barrier();
        __builtin_amdgcn_sched_barrier(0);
        // Prefetch next tile into the freed slot; lands by next barrier.
        if (t + 1 < NTILES) stage(t + 1, cur ^ 1);

        const float eq0 = lds_q[cur][c16];        // esqn, cols 0-15
        const float eq1 = lds_q[cur][16 + c16];   // esqn, cols 16-31
        const int ci0 = (tile0 + t) * 32 + c16;
        const int ci1 = ci0 + 16;

        // All 8 B fragments up-front (32 VGPRs): frag f = ch*2+kh.
        bf16x8 bh[2][2], bl[2][2];
#pragma unroll
        for (int ch = 0; ch < 2; ++ch)
#pragma unroll
            for (int kh = 0; kh < 2; ++kh) {
                const int fo = ((ch * 2 + kh) * 64 + l) * 16;
                bh[ch][kh] = *(const bf16x8*)(&lds[cur][fo]);
                bl[ch][kh] = *(const bf16x8*)(&lds[cur][4096 + fo]);
            }

        // 4 independent quadrant accumulators (C-init = -e^2/2 of own cols).
        f32x4 a00 = {eq0, eq0, eq0, eq0};   // rh0, ch0
        f32x4 a01 = {eq1, eq1, eq1, eq1};   // rh0, ch1
        f32x4 a10 = {eq0, eq0, eq0, eq0};   // rh1, ch0
        f32x4 a11 = {eq1, eq1, eq1, eq1};   // rh1, ch1

        __builtin_amdgcn_s_setprio(1);
#pragma unroll
        for (int kh = 0; kh < 2; ++kh) {
            a00 = __builtin_amdgcn_mfma_f32_16x16x32_bf16(ah[0][kh], bh[0][kh], a00, 0, 0, 0);
            a01 = __builtin_amdgcn_mfma_f32_16x16x32_bf16(ah[0][kh], bh[1][kh], a01, 0, 0, 0);
            a10 = __builtin_amdgcn_mfma_f32_16x16x32_bf16(ah[1][kh], bh[0][kh], a10, 0, 0, 0);
            a11 = __builtin_amdgcn_mfma_f32_16x16x32_bf16(ah[1][kh], bh[1][kh], a11, 0, 0, 0);
            a00 = __builtin_amdgcn_mfma_f32_16x16x32_bf16(ah[0][kh], bl[0][kh], a00, 0, 0, 0);
            a01 = __builtin_amdgcn_mfma_f32_16x16x32_bf16(ah[0][kh], bl[1][kh], a01, 0, 0, 0);
            a10 = __builtin_amdgcn_mfma_f32_16x16x32_bf16(ah[1][kh], bl[0][kh], a10, 0, 0, 0);
            a11 = __builtin_amdgcn_mfma_f32_16x16x32_bf16(ah[1][kh], bl[1][kh], a11, 0, 0, 0);
            a00 = __builtin_amdgcn_mfma_f32_16x16x32_bf16(al[0][kh], bh[0][kh], a00, 0, 0, 0);
            a01 = __builtin_amdgcn_mfma_f32_16x16x32_bf16(al[0][kh], bh[1][kh], a01, 0, 0, 0);
            a10 = __builtin_amdgcn_mfma_f32_16x16x32_bf16(al[1][kh], bh[0][kh], a10, 0, 0, 0);
            a11 = __builtin_amdgcn_mfma_f32_16x16x32_bf16(al[1][kh], bh[1][kh], a11, 0, 0, 0);
        }
        __builtin_amdgcn_s_setprio(0);

        // Track per row: ch0 candidate then ch1 (ascending index -> first-min).
#define TRACK2(V0, V1, E)                                            \
        {                                                            \
            float v0 = (V0), v1 = (V1);                              \
            bool g0 = v0 > b1[E];                                    \
            b2[E] = __builtin_amdgcn_fmed3f(v0, b1[E], b2[E]);       \
            b1[E] = fmaxf(v0, b1[E]);                                \
            i1[E] = g0 ? ci0 : i1[E];                                \
            bool g1 = v1 > b1[E];                                    \
            b2[E] = __builtin_amdgcn_fmed3f(v1, b1[E], b2[E]);       \
            b1[E] = fmaxf(v1, b1[E]);                                \
            i1[E] = g1 ? ci1 : i1[E];                                \
        }
#pragma unroll
        for (int j = 0; j < 4; ++j) {
            TRACK2(a00[j], a01[j], j)
            TRACK2(a10[j], a11[j], 4 + j)
        }
#undef TRACK2
    }

    // Butterfly over the 16 col lanes (xor bits 0-3 preserve rgrp).
#pragma unroll
    for (int e = 0; e < 8; ++e) {
#pragma unroll
        for (int m = 1; m <= 8; m <<= 1) {
            float ob1 = __shfl_xor(b1[e], m);
            float ob2 = __shfl_xor(b2[e], m);
            int oi = __shfl_xor(i1[e], m);
            float nb2 = fmaxf(fminf(b1[e], ob1), fmaxf(b2[e], ob2));
            bool take = ob1 > b1[e];
            b1[e] = take ? ob1 : b1[e];
            i1[e] = take ? oi : i1[e];
            b2[e] = nb2;
        }
        if (c16 == 0) {
            int row = rowbase + (e >> 2) * 16 + rgrp * 4 + (e & 3);  // m89 D-row map
            b1s[(size_t)kc * N_ROWS + row] = b1[e];
            b2s[(size_t)kc * N_ROWS + row] = b2[e];
            i1s[(size_t)kc * N_ROWS + row] = i1[e];
        }
    }
}

// ---------------------------------------------------------------------------
// vq_merge_gather: merge the 2 chunks per row, flag close calls, write
// out_ind + out_q (8 threads per row).
// ---------------------------------------------------------------------------
__global__ __launch_bounds__(256) void vq_merge_gather(const float* __restrict__ embed,
                                                       const float* __restrict__ b1s,
                                                       const float* __restrict__ b2s,
                                                       const int* __restrict__ i1s,
                                                       float* __restrict__ out_q,
                                                       float* __restrict__ out_ind,
                                                       int* __restrict__ list,
                                                       int* __restrict__ count) {
    int t = blockIdx.x * 256 + threadIdx.x;
    int r = t >> 3, q = t & 7;
    float ab1 = b1s[r], bb1 = b1s[N_ROWS + r];
    float ab2 = b2s[r], bb2 = b2s[N_ROWS + r];
    int ai = i1s[r], bi = i1s[N_ROWS + r];
    bool take = bb1 > ab1;                 // tie -> chunk 0 (lower index); ties flagged anyway
    int idx = take ? bi : ai;
    float m1 = fmaxf(ab1, bb1);
    float m2 = fmaxf(fminf(ab1, bb1), fmaxf(ab2, bb2));
    const float4* src = (const float4*)(embed + (size_t)idx * DIM + q * 8);
    float4* dst = (float4*)(out_q + (size_t)r * DIM + q * 8);
    dst[0] = src[0];
    dst[1] = src[1];
    if (q == 0) {
        out_ind[r] = (float)idx;
        if (m1 - m2 < ACC_MARGIN) {
            int p = atomicAdd(count, 1);
            list[p] = r;
        }
    }
}

// ---------------------------------------------------------------------------
// vq_rescore: exact fp32 full rescan of flagged rows; patches out directly.
// ---------------------------------------------------------------------------
__global__ __launch_bounds__(256) void vq_rescore(const float* __restrict__ x,
                                                  const float* __restrict__ embed,
                                                  const float* __restrict__ esq,
                                                  const int* __restrict__ list,
                                                  const int* __restrict__ count,
                                                  float* __restrict__ out_q,
                                                  float* __restrict__ out_ind) {
    __shared__ float xs[64];
    __shared__ float sk[256];
    __shared__ int si[256];
    const int tid = threadIdx.x;
    const int n = *count;
    for (int f = blockIdx.x; f < n; f += gridDim.x) {
        const int row = list[f];
        if (tid < 16) ((float4*)xs)[tid] = ((const float4*)(x + (size_t)row * DIM))[tid];
        __syncthreads();
        float best = 3.0e38f;
        int bi = 0;
        for (int i = 0; i < 16; ++i) {
            int c = tid + (i << 8);
            const float* e = embed + (size_t)c * DIM;
            float d0 = 0, d1 = 0, d2 = 0, d3 = 0;
#pragma unroll
            for (int d = 0; d < 64; d += 4) {
                d0 = fmaf(xs[d + 0], e[d + 0], d0);
                d1 = fmaf(xs[d + 1], e[d + 1], d1);
                d2 = fmaf(xs[d + 2], e[d + 2], d2);
                d3 = fmaf(xs[d + 3], e[d + 3], d3);
            }
            float key = fmaf(-2.f, (d0 + d1) + (d2 + d3), esq[c]);
            if (key < best) { best = key; bi = c; }   // c ascending -> first-min
        }
        sk[tid] = best; si[tid] = bi;
        __syncthreads();
        for (int s = 128; s > 0; s >>= 1) {
            if (tid < s) {
                float ok = sk[tid + s]; int oi = si[tid + s];
                if (ok < sk[tid] || (ok == sk[tid] && oi < si[tid])) { sk[tid] = ok; si[tid] = oi; }
            }
            __syncthreads();
        }
        if (tid == 0) out_ind[row] = (float)si[0];
        if (tid < 16) {
            const float4* src = (const float4*)(embed + (size_t)si[0] * DIM);
            ((float4*)(out_q + (size_t)row * DIM))[tid] = src[tid];
        }
        __syncthreads();
    }
}

// ---------------------------------------------------------------------------
extern "C" void kernel_launch(void* const* d_in, const int* in_sizes, int n_in,
                              void* d_out, int out_size, void* d_ws, size_t ws_size,
                              hipStream_t stream) {
    const float* x = (const float*)d_in[0];      // [N, D] fp32
    const float* embed = (const float*)d_in[1];  // [1, K, D] fp32
    float* out = (float*)d_out;                  // [N*D quantize][N indices]
    float* out_ind = out + (size_t)N_ROWS * DIM;

    char* ws = (char*)d_ws;
    short* e_pk = (short*)ws;                            // 1 MB
    size_t off = 1 << 20;
    float* esq = (float*)(ws + off);  off += 17 << 10;   // 16 KB (+pad)
    float* esqn = (float*)(ws + off); off += 17 << 10;   // 16 KB + 64-float stage pad
    float* b1s = (float*)(ws + off);  off += (size_t)K_CHUNKS * N_ROWS * 4;
    float* b2s = (float*)(ws + off);  off += (size_t)K_CHUNKS * N_ROWS * 4;
    int* i1s = (int*)(ws + off);      off += (size_t)K_CHUNKS * N_ROWS * 4;
    int* list = (int*)(ws + off);     off += (size_t)N_ROWS * 4;
    int* count = (int*)(ws + off);

    pack_e<<<NTILES_TOTAL, 256, 0, stream>>>(embed, e_pk, esq, esqn, count);
    vq_main<<<(N_ROWS / 128) * K_CHUNKS, 256, 0, stream>>>(x, e_pk, esqn, b1s, b2s, i1s);
    vq_merge_gather<<<N_ROWS * 8 / 256, 256, 0, stream>>>(embed, b1s, b2s, i1s,
                                                          out, out_ind, list, count);
    vq_rescore<<<512, 256, 0, stream>>>(x, embed, esq, list, count, out, out_ind);
}

// Round 10
// 139.643 us; speedup vs baseline: 1.7056x; 1.0492x over previous
//
#include <hip/hip_runtime.h>
#include <math.h>

#define N_ROWS 65536
#define K_CODES 4096
#define NTILES_TOTAL (K_CODES / 32)       // 128
#define K_CHUNKS 2
#define NTILES (NTILES_TOTAL / K_CHUNKS)  // 64 tiles per chunk
#define DIM 64
#define ACC_MARGIN 0.005f   // acc-space gap (= 0.01 in key space), ~16x error bound

typedef __attribute__((ext_vector_type(8))) short bf16x8;
typedef __attribute__((ext_vector_type(4))) float f32x4;

__device__ inline unsigned short f2bf_rne(float f) {
    unsigned u = __float_as_uint(f);
    return (unsigned short)((u + 0x7FFFu + ((u >> 16) & 1u)) >> 16);
}
__device__ inline float bf2f(unsigned short s) {
    return __uint_as_float(((unsigned)s) << 16);
}

// ---------------------------------------------------------------------------
// pack_e: 16x16x32 fragment layout. Frag f = ch*2+kh (ch: code half, kh: k half).
// Lane l elem j <- e[tile*32 + ch*16 + (l&15)][kh*32 + ((l>>4)&3)*8 + j].
// Same index formula used for the in-register x split => k-map cancels in A.B.
// hi frags at tile*8KB + f*1KB, lo at +4KB. Also esq, esqn=-esq/2, count=0.
// ---------------------------------------------------------------------------
__global__ __launch_bounds__(256) void pack_e(const float* __restrict__ embed,
                                              short* __restrict__ e_pk,
                                              float* __restrict__ esq,
                                              float* __restrict__ esqn,
                                              int* __restrict__ count) {
    __shared__ float lds_f[2048];   // 32 codes x 64 dims
    const int tile = blockIdx.x;
    const int t = threadIdx.x;
    if (tile == 0 && t == 0) *count = 0;
    const float4* src = (const float4*)(embed + (size_t)tile * 2048);
    ((float4*)lds_f)[t] = src[t];
    ((float4*)lds_f)[t + 256] = src[t + 256];
    __syncthreads();
    const int l = t & 63;
    const int kh = (t >> 6) & 1;
    const int ch = (t >> 7) & 1;
    const int base = (ch * 16 + (l & 15)) * 64 + kh * 32 + ((l >> 4) & 3) * 8;
    bf16x8 vh, vl;
#pragma unroll
    for (int j = 0; j < 8; ++j) {
        float v = lds_f[base + j];
        unsigned short h = f2bf_rne(v);
        vh[j] = (short)h;
        vl[j] = (short)f2bf_rne(v - bf2f(h));
    }
    *(bf16x8*)(e_pk + (size_t)tile * 4096 + t * 8) = vh;          // f*512 + l*8 == t*8
    *(bf16x8*)(e_pk + (size_t)tile * 4096 + 2048 + t * 8) = vl;
    if (t < 32) {
        float s = 0.f;
#pragma unroll
        for (int d = 0; d < 64; ++d) { float v = lds_f[t * 64 + d]; s = fmaf(v, v, s); }
        esq[tile * 32 + t] = s;
        esqn[tile * 32 + t] = -0.5f * s;
    }
}

// ---------------------------------------------------------------------------
// vq_main: wave = 64 rows; block = 4 waves = 256 rows; one K-chunk per block.
// NO LDS, NO barriers: B fragments loaded global->VGPR (e_pk L2-resident,
// coalesced 16B/lane), software-pipelined in even/odd named register sets.
// 8 independent MFMA chains of depth 6 per tile. Waves fully decoupled.
// ---------------------------------------------------------------------------
__global__ __launch_bounds__(256, 2) void vq_main(const float* __restrict__ x,
                                                  const short* __restrict__ e_pk,
                                                  const float* __restrict__ esqn,
                                                  float* __restrict__ b1s,
                                                  float* __restrict__ b2s,
                                                  int* __restrict__ i1s) {
    const int tid = threadIdx.x;
    const int wid = tid >> 6;
    const int l = tid & 63;
    const int c16 = l & 15;          // fragment col index
    const int rgrp = (l >> 4) & 3;   // k-group / D-row-group selector
    const int kc = blockIdx.x & (K_CHUNKS - 1);
    const int rg = blockIdx.x >> 1;
    const int rowbase = rg * 256 + wid * 64;
    const int tile0 = kc * NTILES;

    // A fragments: 4 row-halves x 2 k-halves, hi/lo split (64 VGPRs).
    bf16x8 ah[4][2], al[4][2];
#pragma unroll
    for (int rh = 0; rh < 4; ++rh) {
        const float* xr = x + (size_t)(rowbase + rh * 16 + c16) * DIM;
#pragma unroll
        for (int kh = 0; kh < 2; ++kh) {
            const float* p = xr + kh * 32 + rgrp * 8;
#pragma unroll
            for (int j = 0; j < 8; ++j) {
                float v = p[j];
                unsigned short h = f2bf_rne(v);
                ah[rh][kh][j] = (short)h;
                al[rh][kh][j] = (short)f2bf_rne(v - bf2f(h));
            }
        }
    }

    // Per-row trackers: slot e = rh*4 + j (16 rows this lane contributes to).
    float b1[16], b2[16];
    int i1[16];
#pragma unroll
    for (int i = 0; i < 16; ++i) { b1[i] = -3.0e38f; b2[i] = -3.0e38f; i1[i] = 0; }

    const bf16x8* ep = (const bf16x8*)e_pk;   // 512 bf16x8 per tile block

// Load tile TT's 8 B frags + 2 esqn into a named register set (static idx).
#define LOADB(TT, BH, BL, EQ0, EQ1)                                  \
    {                                                                \
        const bf16x8* bp = ep + (size_t)(TT) * 512;                  \
        _Pragma("unroll")                                            \
        for (int ch = 0; ch < 2; ++ch)                               \
            _Pragma("unroll")                                        \
            for (int kh = 0; kh < 2; ++kh) {                         \
                BH[ch][kh] = bp[(ch * 2 + kh) * 64 + l];             \
                BL[ch][kh] = bp[256 + (ch * 2 + kh) * 64 + l];       \
            }                                                        \
        EQ0 = esqn[(TT) * 32 + c16];                                 \
        EQ1 = esqn[(TT) * 32 + 16 + c16];                            \
    }

#define TRACK2(V0, V1, E, CI0, CI1)                                  \
        {                                                            \
            float v0 = (V0), v1 = (V1);                              \
            bool g0 = v0 > b1[E];                                    \
            b2[E] = __builtin_amdgcn_fmed3f(v0, b1[E], b2[E]);       \
            b1[E] = fmaxf(v0, b1[E]);                                \
            i1[E] = g0 ? (CI0) : i1[E];                              \
            bool g1 = v1 > b1[E];                                    \
            b2[E] = __builtin_amdgcn_fmed3f(v1, b1[E], b2[E]);       \
            b1[E] = fmaxf(v1, b1[E]);                                \
            i1[E] = g1 ? (CI1) : i1[E];                              \
        }

// Compute global tile TT from a named register set: 48 MFMA (8 chains x 6).
#define COMPUTE(TT, BH, BL, EQ0, EQ1)                                \
    {                                                                \
        const int ci0 = (TT) * 32 + c16;                             \
        const int ci1 = ci0 + 16;                                    \
        f32x4 acc[4][2];                                             \
        _Pragma("unroll")                                            \
        for (int rh = 0; rh < 4; ++rh) {                             \
            acc[rh][0] = (f32x4){EQ0, EQ0, EQ0, EQ0};                \
            acc[rh][1] = (f32x4){EQ1, EQ1, EQ1, EQ1};                \
        }                                                            \
        __builtin_amdgcn_s_setprio(1);                               \
        _Pragma("unroll")                                            \
        for (int kh = 0; kh < 2; ++kh)                               \
            _Pragma("unroll")                                        \
            for (int rh = 0; rh < 4; ++rh) {                         \
                acc[rh][0] = __builtin_amdgcn_mfma_f32_16x16x32_bf16(ah[rh][kh], BH[0][kh], acc[rh][0], 0, 0, 0); \
                acc[rh][1] = __builtin_amdgcn_mfma_f32_16x16x32_bf16(ah[rh][kh], BH[1][kh], acc[rh][1], 0, 0, 0); \
                acc[rh][0] = __builtin_amdgcn_mfma_f32_16x16x32_bf16(ah[rh][kh], BL[0][kh], acc[rh][0], 0, 0, 0); \
                acc[rh][1] = __builtin_amdgcn_mfma_f32_16x16x32_bf16(ah[rh][kh], BL[1][kh], acc[rh][1], 0, 0, 0); \
                acc[rh][0] = __builtin_amdgcn_mfma_f32_16x16x32_bf16(al[rh][kh], BH[0][kh], acc[rh][0], 0, 0, 0); \
                acc[rh][1] = __builtin_amdgcn_mfma_f32_16x16x32_bf16(al[rh][kh], BH[1][kh], acc[rh][1], 0, 0, 0); \
            }                                                        \
        __builtin_amdgcn_s_setprio(0);                               \
        _Pragma("unroll")                                            \
        for (int rh = 0; rh < 4; ++rh)                               \
            _Pragma("unroll")                                        \
            for (int j = 0; j < 4; ++j)                              \
                TRACK2(acc[rh][0][j], acc[rh][1][j], rh * 4 + j, ci0, ci1) \
    }

    // Software pipeline: even/odd named B register sets, no sync objects.
    bf16x8 bhA[2][2], blA[2][2], bhB[2][2], blB[2][2];
    float eqA0, eqA1, eqB0, eqB1;

    LOADB(tile0, bhA, blA, eqA0, eqA1);
#pragma unroll 1
    for (int t = 0; t < NTILES; t += 2) {
        const int gt1 = tile0 + t + 1;                        // always < tile0+NTILES
        const int gt2 = tile0 + min(t + 2, NTILES - 1);       // clamped (dup load ok)
        LOADB(gt1, bhB, blB, eqB0, eqB1);
        COMPUTE(tile0 + t, bhA, blA, eqA0, eqA1);
        LOADB(gt2, bhA, blA, eqA0, eqA1);
        COMPUTE(gt1, bhB, blB, eqB0, eqB1);
    }
#undef LOADB
#undef COMPUTE
#undef TRACK2

    // Butterfly over the 16 col lanes (xor bits 0-3 preserve rgrp).
#pragma unroll
    for (int e = 0; e < 16; ++e) {
#pragma unroll
        for (int m = 1; m <= 8; m <<= 1) {
            float ob1 = __shfl_xor(b1[e], m);
            float ob2 = __shfl_xor(b2[e], m);
            int oi = __shfl_xor(i1[e], m);
            float nb2 = fmaxf(fminf(b1[e], ob1), fmaxf(b2[e], ob2));
            bool take = ob1 > b1[e];
            b1[e] = take ? ob1 : b1[e];
            i1[e] = take ? oi : i1[e];
            b2[e] = nb2;
        }
        if (c16 == 0) {
            int row = rowbase + (e >> 2) * 16 + rgrp * 4 + (e & 3);  // m89 D-row map
            b1s[(size_t)kc * N_ROWS + row] = b1[e];
            b2s[(size_t)kc * N_ROWS + row] = b2[e];
            i1s[(size_t)kc * N_ROWS + row] = i1[e];
        }
    }
}

// ---------------------------------------------------------------------------
// vq_merge_gather: merge the 2 chunks per row, flag close calls, write
// out_ind + out_q (8 threads per row).
// ---------------------------------------------------------------------------
__global__ __launch_bounds__(256) void vq_merge_gather(const float* __restrict__ embed,
                                                       const float* __restrict__ b1s,
                                                       const float* __restrict__ b2s,
                                                       const int* __restrict__ i1s,
                                                       float* __restrict__ out_q,
                                                       float* __restrict__ out_ind,
                                                       int* __restrict__ list,
                                                       int* __restrict__ count) {
    int t = blockIdx.x * 256 + threadIdx.x;
    int r = t >> 3, q = t & 7;
    float ab1 = b1s[r], bb1 = b1s[N_ROWS + r];
    float ab2 = b2s[r], bb2 = b2s[N_ROWS + r];
    int ai = i1s[r], bi = i1s[N_ROWS + r];
    bool take = bb1 > ab1;                 // tie -> chunk 0 (lower index); ties flagged anyway
    int idx = take ? bi : ai;
    float m1 = fmaxf(ab1, bb1);
    float m2 = fmaxf(fminf(ab1, bb1), fmaxf(ab2, bb2));
    const float4* src = (const float4*)(embed + (size_t)idx * DIM + q * 8);
    float4* dst = (float4*)(out_q + (size_t)r * DIM + q * 8);
    dst[0] = src[0];
    dst[1] = src[1];
    if (q == 0) {
        out_ind[r] = (float)idx;
        if (m1 - m2 < ACC_MARGIN) {
            int p = atomicAdd(count, 1);
            list[p] = r;
        }
    }
}

// ---------------------------------------------------------------------------
// vq_rescore: exact fp32 full rescan of flagged rows; patches out directly.
// ---------------------------------------------------------------------------
__global__ __launch_bounds__(256) void vq_rescore(const float* __restrict__ x,
                                                  const float* __restrict__ embed,
                                                  const float* __restrict__ esq,
                                                  const int* __restrict__ list,
                                                  const int* __restrict__ count,
                                                  float* __restrict__ out_q,
                                                  float* __restrict__ out_ind) {
    __shared__ float xs[64];
    __shared__ float sk[256];
    __shared__ int si[256];
    const int tid = threadIdx.x;
    const int n = *count;
    for (int f = blockIdx.x; f < n; f += gridDim.x) {
        const int row = list[f];
        if (tid < 16) ((float4*)xs)[tid] = ((const float4*)(x + (size_t)row * DIM))[tid];
        __syncthreads();
        float best = 3.0e38f;
        int bi = 0;
        for (int i = 0; i < 16; ++i) {
            int c = tid + (i << 8);
            const float* e = embed + (size_t)c * DIM;
            float d0 = 0, d1 = 0, d2 = 0, d3 = 0;
#pragma unroll
            for (int d = 0; d < 64; d += 4) {
                d0 = fmaf(xs[d + 0], e[d + 0], d0);
                d1 = fmaf(xs[d + 1], e[d + 1], d1);
                d2 = fmaf(xs[d + 2], e[d + 2], d2);
                d3 = fmaf(xs[d + 3], e[d + 3], d3);
            }
            float key = fmaf(-2.f, (d0 + d1) + (d2 + d3), esq[c]);
            if (key < best) { best = key; bi = c; }   // c ascending -> first-min
        }
        sk[tid] = best; si[tid] = bi;
        __syncthreads();
        for (int s = 128; s > 0; s >>= 1) {
            if (tid < s) {
                float ok = sk[tid + s]; int oi = si[tid + s];
                if (ok < sk[tid] || (ok == sk[tid] && oi < si[tid])) { sk[tid] = ok; si[tid] = oi; }
            }
            __syncthreads();
        }
        if (tid == 0) out_ind[row] = (float)si[0];
        if (tid < 16) {
            const float4* src = (const float4*)(embed + (size_t)si[0] * DIM);
            ((float4*)(out_q + (size_t)row * DIM))[tid] = src[tid];
        }
        __syncthreads();
    }
}

// ---------------------------------------------------------------------------
extern "C" void kernel_launch(void* const* d_in, const int* in_sizes, int n_in,
                              void* d_out, int out_size, void* d_ws, size_t ws_size,
                              hipStream_t stream) {
    const float* x = (const float*)d_in[0];      // [N, D] fp32
    const float* embed = (const float*)d_in[1];  // [1, K, D] fp32
    float* out = (float*)d_out;                  // [N*D quantize][N indices]
    float* out_ind = out + (size_t)N_ROWS * DIM;

    char* ws = (char*)d_ws;
    short* e_pk = (short*)ws;                            // 1 MB
    size_t off = 1 << 20;
    float* esq = (float*)(ws + off);  off += 17 << 10;   // 16 KB (+pad)
    float* esqn = (float*)(ws + off); off += 17 << 10;   // 16 KB (+pad)
    float* b1s = (float*)(ws + off);  off += (size_t)K_CHUNKS * N_ROWS * 4;
    float* b2s = (float*)(ws + off);  off += (size_t)K_CHUNKS * N_ROWS * 4;
    int* i1s = (int*)(ws + off);      off += (size_t)K_CHUNKS * N_ROWS * 4;
    int* list = (int*)(ws + off);     off += (size_t)N_ROWS * 4;
    int* count = (int*)(ws + off);

    pack_e<<<NTILES_TOTAL, 256, 0, stream>>>(embed, e_pk, esq, esqn, count);
    vq_main<<<(N_ROWS / 256) * K_CHUNKS, 256, 0, stream>>>(x, e_pk, esqn, b1s, b2s, i1s);
    vq_merge_gather<<<N_ROWS * 8 / 256, 256, 0, stream>>>(embed, b1s, b2s, i1s,
                                                          out, out_ind, list, count);
    vq_rescore<<<512, 256, 0, stream>>>(x, embed, esq, list, count, out, out_ind);
}